// Round 10
// baseline (441.468 us; speedup 1.0000x reference)
//
#include <hip/hip_runtime.h>
#include <hip/hip_fp16.h>
#include <math.h>

constexpr int D = 64;
constexpr int BROWS = 128;          // dst rows per bucket (bucket = dst >> 7)
constexpr int BCAP  = 6016;         // record capacity per bucket (mult of 4)
constexpr int PASS1_CHUNK = 4096;   // edges per workgroup in pass 1
constexpr int SCAP = 8192;          // LDS staging records (= 2*PASS1_CHUNK)
constexpr int NB2  = 1184;          // padded bucket count for LDS arrays
constexpr int BPT  = 5;             // buckets per thread in local scan
constexpr int WROW = 136;           // fp16 LDS row stride (128 + 8 pad)

typedef _Float16 half8 __attribute__((ext_vector_type(8)));
typedef float    f32x4 __attribute__((ext_vector_type(4)));

__device__ __forceinline__ float wave_reduce_sum(float v) {
    #pragma unroll
    for (int m = 1; m < 64; m <<= 1)
        v += __shfl_xor(v, m, 64);
    return v;
}

__device__ __forceinline__ void h8_to_f8(uint4 h, float* f) {
    const __half2* hp = reinterpret_cast<const __half2*>(&h);
    #pragma unroll
    for (int i = 0; i < 4; ++i) {
        float2 t = __half22float2(hp[i]);
        f[2 * i] = t.x; f[2 * i + 1] = t.y;
    }
}

__device__ __forceinline__ uint4 f8_to_h8(const float* f) {
    uint4 r;
    unsigned* rp = &r.x;
    #pragma unroll
    for (int i = 0; i < 4; ++i) {
        __half2 h = __floats2half2_rn(f[2 * i], f[2 * i + 1]);
        rp[i] = *reinterpret_cast<unsigned*>(&h);
    }
    return r;
}

// ---- L0 fused: item projection (MFMA GEMM) + user l2norm.
//      Blocks [0, IB): 64 items/block.  Blocks [IB, IB+UB): 16 user rows
//      per block (4 per wave).  Both write y0 = dinv * l2norm(.).
__global__ void __launch_bounds__(256) k_l0(
        const float* __restrict__ audio,
        const float* __restrict__ artist_w, const float* __restrict__ album_w,
        const float* __restrict__ proj_W,   const float* __restrict__ proj_b,
        const int* __restrict__ artist_ids, const int* __restrict__ album_ids,
        const float* __restrict__ user_w,   const float* __restrict__ dinv,
        __half* __restrict__ x, int I_, int U_, int IB) {
    __shared__ __align__(16) __half Wh[64 * WROW];      // proj_W in fp16
    __shared__ __align__(16) __half feat[4 * 16 * WROW]; // per-wave 16x128

    const int tid  = threadIdx.x;
    const int lane = tid & 63;
    const int wv   = tid >> 6;

    if ((int)blockIdx.x >= IB) {
        // ---- user path: 4 rows per wave ----
        int base = ((int)blockIdx.x - IB) * 16 + wv * 4;
        #pragma unroll
        for (int k = 0; k < 4; ++k) {
            int row = base + k;
            if (row < U_) {
                size_t o = (size_t)row * D + lane;
                float v  = user_w[o];
                float ss = wave_reduce_sum(v * v);
                x[o] = __float2half(dinv[row] * v / fmaxf(sqrtf(ss), 1e-12f));
            }
        }
        return;
    }

    // ---- item path ----
    const int n    = lane & 15;       // d within tile / m within tile
    const int quad = lane >> 4;

    for (int idx = tid; idx < 64 * 128; idx += 256) {
        int d = idx >> 7, k = idx & 127;
        Wh[d * WROW + k] = __float2half(proj_W[idx]);
    }
    __syncthreads();

    half8 bfrag[4][4];
    #pragma unroll
    for (int dg = 0; dg < 4; ++dg)
        #pragma unroll
        for (int c = 0; c < 4; ++c)
            bfrag[dg][c] = *reinterpret_cast<const half8*>(
                &Wh[(dg * 16 + n) * WROW + c * 32 + quad * 8]);

    __half* fw = &feat[wv * 16 * WROW];
    const int itemBase = blockIdx.x * 64 + wv * 16;
    #pragma unroll 4
    for (int it = 0; it < 16; ++it) {
        int item = itemBase + it;
        float a = 0.f, m = 0.f;
        if (item < I_) {
            a = audio[(size_t)item * D + lane];
            int aid = artist_ids[item], bid = album_ids[item];
            m = artist_w[(size_t)aid * D + lane] +
                album_w[(size_t)bid * D + lane];
        }
        fw[it * WROW + lane]      = __float2half(a);
        fw[it * WROW + 64 + lane] = __float2half(m);
    }
    __syncthreads();

    half8 afrag[4];
    #pragma unroll
    for (int c = 0; c < 4; ++c)
        afrag[c] = *reinterpret_cast<const half8*>(
            &fw[n * WROW + c * 32 + quad * 8]);

    f32x4 acc[4];
    #pragma unroll
    for (int dg = 0; dg < 4; ++dg) {
        f32x4 t = {0.f, 0.f, 0.f, 0.f};
        #pragma unroll
        for (int c = 0; c < 4; ++c)
            t = __builtin_amdgcn_mfma_f32_16x16x32_f16(afrag[c], bfrag[dg][c],
                                                       t, 0, 0, 0);
        acc[dg] = t;
    }

    float bias[4];
    #pragma unroll
    for (int dg = 0; dg < 4; ++dg) bias[dg] = proj_b[dg * 16 + n];

    float val[4][4], ss[4];
    #pragma unroll
    for (int r = 0; r < 4; ++r) {
        float s = 0.f;
        #pragma unroll
        for (int dg = 0; dg < 4; ++dg) {
            float v = acc[dg][r] + bias[dg];
            val[dg][r] = v;
            s = fmaf(v, v, s);
        }
        s += __shfl_xor(s, 1, 64);
        s += __shfl_xor(s, 2, 64);
        s += __shfl_xor(s, 4, 64);
        s += __shfl_xor(s, 8, 64);
        ss[r] = s;
    }

    #pragma unroll
    for (int r = 0; r < 4; ++r) {
        int item = itemBase + quad * 4 + r;
        if (item >= I_) continue;
        float inv = dinv[U_ + item] / fmaxf(sqrtf(ss[r]), 1e-12f);
        size_t rowo = (size_t)(U_ + item) * D + n;
        #pragma unroll
        for (int dg = 0; dg < 4; ++dg)
            x[rowo + dg * 16] = __float2half(val[dg][r] * inv);
    }
}

// ---- pass 1: LDS-staged bucket-sorted scatter (R8-verified) with
//      shfl-based local scan (1 barrier instead of 16).
//      rec.x = wfix14<<18|src18 (final ent word), rec.y(out) = dst_local.
__global__ void __launch_bounds__(256) k_scatter1(
        const int* __restrict__ u_idx, const int* __restrict__ i_idx,
        const float* __restrict__ ew,
        uint2* __restrict__ records, int* __restrict__ gCursor,
        int E_, int U_, int NB) {
    __shared__ uint2 s_rec[SCAP];       // 64 KB
    __shared__ int hist[NB2];           // per-bucket counts
    __shared__ int cur[NB2];            // local start, then running cursor
    __shared__ int diff[NB2];           // gbase - local start
    __shared__ int wtot[4];
    const int tid = threadIdx.x;
    const int lane = tid & 63;
    const int wv   = tid >> 6;
    const int e0 = blockIdx.x * PASS1_CHUNK;
    int uu[16], vv[16]; unsigned wq[16];
    for (int b = tid; b < NB2; b += 256) hist[b] = 0;
    __syncthreads();
    #pragma unroll
    for (int j = 0; j < 16; ++j) {
        int e = e0 + j * 256 + tid;
        uu[j] = -1;
        if (e < E_) {
            int u = __builtin_nontemporal_load(u_idx + e);
            int v = U_ + __builtin_nontemporal_load(i_idx + e);
            float w = fmaxf(__builtin_nontemporal_load(ew + e), 1e-6f);
            unsigned wfix = (unsigned)fminf(w * 16384.f + 0.5f, 16383.f);
            uu[j] = u; vv[j] = v; wq[j] = wfix << 18;
            atomicAdd(&hist[u >> 7], 1);
            atomicAdd(&hist[v >> 7], 1);
        }
    }
    __syncthreads();
    // reserve global bases per bucket (counts stay intact in hist)
    for (int b = tid; b < NB; b += 256) {
        int c = hist[b];
        diff[b] = c ? atomicAdd(&gCursor[b], c) : 0;
    }
    // local exclusive scan over buckets -> cur (shfl wave scan + handoff)
    const int b0 = tid * BPT;
    int cc[BPT]; int s = 0;
    #pragma unroll
    for (int k = 0; k < BPT; ++k) {
        int b = b0 + k;
        cc[k] = (b < NB2) ? hist[b] : 0;
        s += cc[k];
    }
    int incl = s;
    #pragma unroll
    for (int off = 1; off < 64; off <<= 1) {
        int t = __shfl_up(incl, off, 64);
        if (lane >= off) incl += t;
    }
    if (lane == 63) wtot[wv] = incl;
    __syncthreads();
    int add = 0;
    #pragma unroll
    for (int w = 0; w < 4; ++w) add += (w < wv) ? wtot[w] : 0;
    int run = incl - s + add;           // exclusive prefix over threads
    #pragma unroll
    for (int k = 0; k < BPT; ++k) {
        int b = b0 + k;
        if (b < NB2) cur[b] = run;
        run += cc[k];
    }
    __syncthreads();
    // diff = gbase - local start (must complete before cur is mutated)
    for (int b = tid; b < NB; b += 256) diff[b] -= cur[b];
    __syncthreads();
    // place records bucket-sorted into LDS
    #pragma unroll
    for (int j = 0; j < 16; ++j) {
        if (uu[j] >= 0) {
            int u = uu[j], v = vv[j];
            int bu = u >> 7, bv = v >> 7;
            int pu = atomicAdd(&cur[bu], 1);
            s_rec[pu] = make_uint2(wq[j] | (unsigned)v,
                                   (unsigned)(u & 127) | ((unsigned)bu << 7));
            int pv = atomicAdd(&cur[bv], 1);
            s_rec[pv] = make_uint2(wq[j] | (unsigned)u,
                                   (unsigned)(v & 127) | ((unsigned)bv << 7));
        }
    }
    __syncthreads();
    // coalesced output: consecutive p -> consecutive addresses per run
    int nE = E_ - e0; if (nE > PASS1_CHUNK) nE = PASS1_CHUNK;
    const int Rtot = (nE > 0) ? 2 * nE : 0;
    for (int p = tid; p < Rtot; p += 256) {
        uint2 r = s_rec[p];
        int b = (int)(r.y >> 7);
        int goff = diff[b] + p;            // gbase + (p - lstart)
        if (goff < BCAP)
            records[(size_t)b * BCAP + goff] = make_uint2(r.x, r.y & 127u);
    }
}

// ---- pass 2: per bucket, LDS counting-sort.  gbase computed inline;
//      shfl-based 128-row scan (1 barrier).  Single NT pass over records.
//      ents[pos] = entword verbatim.  dinv = rsqrt(iw/2^14 + 1).
__global__ void __launch_bounds__(256) k_build(
        const uint2* __restrict__ rec,
        const int* __restrict__ gCursor,
        unsigned* __restrict__ ents, int* __restrict__ rowptr,
        float* __restrict__ dinv, int N_, int NB) {
    __shared__ unsigned      s_ent[BCAP];   // 24064 B
    __shared__ unsigned char s_dl[BCAP];    //  6016 B
    __shared__ int   s_cnt[BROWS];
    __shared__ int   s_cur[BROWS];
    __shared__ int   s_iw[BROWS];
    __shared__ int   s_red[256];
    __shared__ int   wt2[2];
    const int b   = blockIdx.x;
    const int tid = threadIdx.x;
    const int lane = tid & 63;
    const int R   = min(gCursor[b], BCAP);
    if (tid < BROWS) { s_cnt[tid] = 0; s_iw[tid] = 0; }
    // inline exclusive prefix: gbase = sum_{i<b} min(gCursor[i], BCAP)
    int psum = 0;
    for (int i = tid; i < b; i += 256) psum += min(gCursor[i], BCAP);
    s_red[tid] = psum;
    __syncthreads();
    for (int off = 128; off > 0; off >>= 1) {
        if (tid < off) s_red[tid] += s_red[tid + off];
        __syncthreads();
    }
    const int gbase = s_red[0];
    // stage + count in one NT pass over global records
    const unsigned long long* rb8 =
        reinterpret_cast<const unsigned long long*>(rec + (size_t)b * BCAP);
    for (int r = tid; r < R; r += 256) {
        unsigned long long rv = __builtin_nontemporal_load(rb8 + r);
        unsigned vx = (unsigned)rv;
        unsigned vy = (unsigned)(rv >> 32);
        s_ent[r] = vx;
        s_dl[r]  = (unsigned char)vy;
        atomicAdd(&s_cnt[vy & 127u], 1);
    }
    __syncthreads();
    // exclusive scan over 128 rows via 2-wave shfl scan
    int own = (tid < BROWS) ? s_cnt[tid] : 0;
    int incl = own;
    #pragma unroll
    for (int off = 1; off < 64; off <<= 1) {
        int t = __shfl_up(incl, off, 64);
        if (lane >= off) incl += t;
    }
    if (tid < BROWS && lane == 63) wt2[tid >> 6] = incl;
    __syncthreads();
    if (tid < BROWS) {
        int excl = incl - own + ((tid >= 64) ? wt2[0] : 0);
        s_cur[tid] = excl;
        int gid = b * BROWS + tid;
        if (gid < N_) rowptr[gid] = gbase + excl;
    }
    if (b == NB - 1 && tid == 0) rowptr[N_] = gbase + R;
    __syncthreads();
    // place from LDS; ent word stored verbatim; iw accumulates wfix
    for (int r = tid; r < R; r += 256) {
        int dl = (int)s_dl[r];
        unsigned ev = s_ent[r];
        int pos = gbase + atomicAdd(&s_cur[dl], 1);
        ents[pos] = ev;
        atomicAdd(&s_iw[dl], (int)(ev >> 18));
    }
    __syncthreads();
    // dinv = rsqrt(iw/16384 + 1)
    if (tid < BROWS) {
        int gid = b * BROWS + tid;
        if (gid < N_)
            dinv[gid] = 1.0f / sqrtf((float)s_iw[tid] * (1.0f / 16384.0f) + 1.0f);
    }
}

// ---- propagation layer in y-domain: s = y[dst] + 2^-14 * sum wfix*y[src];
//      y_next = dinv^2 * s.  8-lane row groups, half8 (16 B) per lane.
//      MLP-deep (round-2 structure, best measured): group g owns the
//      contiguous span [beg+g*L, beg+(g+1)*L), L=ceil(deg/8), predicated
//      batches of 4.  ents loads nontemporal (single-use stream; keep L2
//      for the hot y rows).  mode-2 output stores nontemporal.
// mode 0: write yn = y1; ysum = y0 + y1
// mode 1: write yn = y2; ysum += y2
// mode 2: out = l2norm(ysum + y3)        (yn unused)
__global__ void __launch_bounds__(256) k_gather(
        const uint4* __restrict__ ys, uint4* __restrict__ yn,
        uint4* __restrict__ ysum, float4* __restrict__ outp,
        const float* __restrict__ dinv, const int* __restrict__ rowptr,
        const unsigned* __restrict__ ents, int N_, int mode) {
    const int lane = threadIdx.x & 63;
    const int g  = lane >> 3;            // edge group 0..7
    const int c8 = lane & 7;             // half8 index within row
    const int wid = __builtin_amdgcn_readfirstlane(
                        (int)((blockIdx.x * blockDim.x + threadIdx.x) >> 6));
    if (wid >= N_) return;
    const int beg = rowptr[wid], end = rowptr[wid + 1];
    const size_t ro = (size_t)wid * 8 + c8;

    // hoisted epilogue operands — issue early, consume after the loop
    const float di = dinv[wid];
    uint4 hold, hsum;
    if (mode == 2 || g < 2)                  hold = ys[ro];
    if (mode == 2 || (mode == 1 && g == 1))  hsum = ysum[ro];

    const int deg = end - beg;
    const int L   = (deg + 7) >> 3;          // per-group contiguous span
    int j         = beg + g * L;
    const int je  = min(j + L, end);

    float a[8] = {0.f, 0.f, 0.f, 0.f, 0.f, 0.f, 0.f, 0.f};
    while (j < je) {
        int m = je - j; if (m > 4) m = 4;
        unsigned e[4];
        uint4 h[4];
        e[0] = __builtin_nontemporal_load(ents + j);
        if (m > 1) e[1] = __builtin_nontemporal_load(ents + j + 1);
        if (m > 2) e[2] = __builtin_nontemporal_load(ents + j + 2);
        if (m > 3) e[3] = __builtin_nontemporal_load(ents + j + 3);
        h[0] = ys[(size_t)(e[0] & 0x3FFFFu) * 8 + c8];
        if (m > 1) h[1] = ys[(size_t)(e[1] & 0x3FFFFu) * 8 + c8];
        if (m > 2) h[2] = ys[(size_t)(e[2] & 0x3FFFFu) * 8 + c8];
        if (m > 3) h[3] = ys[(size_t)(e[3] & 0x3FFFFu) * 8 + c8];
        #pragma unroll
        for (int t = 0; t < 4; ++t) {
            if (t < m) {
                float wf = (float)(e[t] >> 18);
                const __half2* hp = reinterpret_cast<const __half2*>(&h[t]);
                #pragma unroll
                for (int i = 0; i < 4; ++i) {
                    float2 f2 = __half22float2(hp[i]);
                    a[2 * i]     = fmaf(wf, f2.x, a[2 * i]);
                    a[2 * i + 1] = fmaf(wf, f2.y, a[2 * i + 1]);
                }
            }
        }
        j += 4;
    }

    // reduce the 8 group partials (lanes sharing c8)
    #pragma unroll
    for (int i = 0; i < 8; ++i) {
        a[i] += __shfl_xor(a[i], 8, 64);
        a[i] += __shfl_xor(a[i], 16, 64);
        a[i] += __shfl_xor(a[i], 32, 64);
    }

    float yold[8]; h8_to_f8(hold, yold);
    float d2 = di * di;
    float fin[8];
    #pragma unroll
    for (int i = 0; i < 8; ++i)
        fin[i] = d2 * fmaf(a[i], 1.0f / 16384.0f, yold[i]);

    if (mode == 2) {
        float vs[8]; h8_to_f8(hsum, vs);
        float vv[8], sq = 0.f;
        #pragma unroll
        for (int i = 0; i < 8; ++i) {
            vv[i] = vs[i] + fin[i];
            sq = fmaf(vv[i], vv[i], sq);
        }
        sq += __shfl_xor(sq, 1, 64);
        sq += __shfl_xor(sq, 2, 64);
        sq += __shfl_xor(sq, 4, 64);
        float inv = 1.0f / fmaxf(sqrtf(sq), 1e-12f);
        if (g == 0) {
            size_t ob = (size_t)wid * 16 + c8 * 2;
            f32x4* op = reinterpret_cast<f32x4*>(outp);
            f32x4 v0 = {vv[0] * inv, vv[1] * inv, vv[2] * inv, vv[3] * inv};
            f32x4 v1 = {vv[4] * inv, vv[5] * inv, vv[6] * inv, vv[7] * inv};
            __builtin_nontemporal_store(v0, op + ob);
            __builtin_nontemporal_store(v1, op + ob + 1);
        }
    } else {
        if (g == 0) yn[ro] = f8_to_h8(fin);
        if (g == 1) {
            float t[8];
            if (mode == 0) {
                #pragma unroll
                for (int i = 0; i < 8; ++i) t[i] = yold[i] + fin[i];
            } else {
                float vs[8]; h8_to_f8(hsum, vs);
                #pragma unroll
                for (int i = 0; i < 8; ++i) t[i] = vs[i] + fin[i];
            }
            ysum[ro] = f8_to_h8(t);
        }
    }
}

extern "C" void kernel_launch(void* const* d_in, const int* in_sizes, int n_in,
                              void* d_out, int out_size, void* d_ws, size_t ws_size,
                              hipStream_t stream) {
    const float* user_w     = (const float*)d_in[0];
    const float* audio      = (const float*)d_in[1];
    const float* artist_w   = (const float*)d_in[2];
    const float* album_w    = (const float*)d_in[3];
    const float* proj_W     = (const float*)d_in[4];
    const float* proj_b     = (const float*)d_in[5];
    const float* ew         = (const float*)d_in[6];
    const int*   u_idx      = (const int*)d_in[7];
    const int*   i_idx      = (const int*)d_in[8];
    const int*   artist_ids = (const int*)d_in[9];
    const int*   album_ids  = (const int*)d_in[10];

    const int U_ = in_sizes[0] / D;
    const int I_ = in_sizes[1] / D;
    const int E_ = in_sizes[6];
    const int N_ = U_ + I_;
    const int NB = (N_ + BROWS - 1) / BROWS;    // 1172

    size_t xbytes = (size_t)N_ * D * sizeof(__half);      // 19.2 MB
    size_t recbytes = (size_t)NB * BCAP * sizeof(uint2);  // 56.4 MB
    size_t rreg = 2 * xbytes > recbytes ? 2 * xbytes : recbytes;

    char* p = (char*)d_ws;
    __half* yA = (__half*)p;            p += xbytes;
    char* R = p;                        p += rreg;
    __half* yB   = (__half*)R;                           // aliases records
    __half* ysum = (__half*)(R + xbytes);                // (records dead by then)
    uint2* records = (uint2*)R;
    unsigned* ents = (unsigned*)p;      p += (size_t)2 * E_ * sizeof(unsigned);
    int*   rowptr = (int*)p;            p += (size_t)(N_ + 1) * 4;
    float* dinv   = (float*)p;          p += (size_t)N_ * 4;
    int*   gCursor    = (int*)p;        p += (size_t)NB * 4;

    hipMemsetAsync(gCursor, 0, (size_t)NB * 4, stream);

    // adjacency build first: scatter -> sort+rowptr+dinv
    k_scatter1<<<(E_ + PASS1_CHUNK - 1) / PASS1_CHUNK, 256, 0, stream>>>(
        u_idx, i_idx, ew, records, gCursor, E_, U_, NB);
    k_build<<<NB, 256, 0, stream>>>(records, gCursor,
                                    ents, rowptr, dinv, N_, NB);

    // L0 embeddings -> yA, pre-scaled by dinv (y0 = dinv * x0), fused kernel
    const int IB = (I_ + 63) / 64;
    const int UB = (U_ + 15) / 16;
    k_l0<<<IB + UB, 256, 0, stream>>>(audio, artist_w, album_w, proj_W, proj_b,
                                      artist_ids, album_ids, user_w, dinv,
                                      yA, I_, U_, IB);

    // 3 layers in y-domain; out = l2norm(y0+y1+y2+y3)
    const int ggrid = (N_ + 3) / 4;
    k_gather<<<ggrid, 256, 0, stream>>>((uint4*)yA, (uint4*)yB, (uint4*)ysum,
                                        (float4*)d_out, dinv, rowptr, ents, N_, 0);
    k_gather<<<ggrid, 256, 0, stream>>>((uint4*)yB, (uint4*)yA, (uint4*)ysum,
                                        (float4*)d_out, dinv, rowptr, ents, N_, 1);
    k_gather<<<ggrid, 256, 0, stream>>>((uint4*)yA, (uint4*)yB, (uint4*)ysum,
                                        (float4*)d_out, dinv, rowptr, ents, N_, 2);
}

// Round 11
// 429.335 us; speedup vs baseline: 1.0283x; 1.0283x over previous
//
#include <hip/hip_runtime.h>
#include <hip/hip_fp16.h>
#include <math.h>

constexpr int D = 64;
constexpr int BROWS = 128;          // dst rows per bucket (bucket = dst >> 7)
constexpr int BCAP  = 6016;         // record capacity per bucket (mult of 4)
constexpr int PASS1_CHUNK = 4096;   // edges per workgroup in pass 1
constexpr int SCAP = 8192;          // LDS staging records (= 2*PASS1_CHUNK)
constexpr int NB2  = 1184;          // padded bucket count for LDS arrays
constexpr int BPT  = 5;             // buckets per thread in local scan
constexpr int WROW = 136;           // fp16 LDS row stride (128 + 8 pad)

typedef _Float16 half8 __attribute__((ext_vector_type(8)));
typedef float    f32x4 __attribute__((ext_vector_type(4)));

__device__ __forceinline__ float wave_reduce_sum(float v) {
    #pragma unroll
    for (int m = 1; m < 64; m <<= 1)
        v += __shfl_xor(v, m, 64);
    return v;
}

__device__ __forceinline__ void h8_to_f8(uint4 h, float* f) {
    const __half2* hp = reinterpret_cast<const __half2*>(&h);
    #pragma unroll
    for (int i = 0; i < 4; ++i) {
        float2 t = __half22float2(hp[i]);
        f[2 * i] = t.x; f[2 * i + 1] = t.y;
    }
}

__device__ __forceinline__ uint4 f8_to_h8(const float* f) {
    uint4 r;
    unsigned* rp = &r.x;
    #pragma unroll
    for (int i = 0; i < 4; ++i) {
        __half2 h = __floats2half2_rn(f[2 * i], f[2 * i + 1]);
        rp[i] = *reinterpret_cast<unsigned*>(&h);
    }
    return r;
}

// ---- L0 fused: item projection (MFMA GEMM) + user l2norm.
//      Blocks [0, IB): 64 items/block.  Blocks [IB, IB+UB): 16 user rows
//      per block (4 per wave).  Both write y0 = dinv * l2norm(.).
__global__ void __launch_bounds__(256) k_l0(
        const float* __restrict__ audio,
        const float* __restrict__ artist_w, const float* __restrict__ album_w,
        const float* __restrict__ proj_W,   const float* __restrict__ proj_b,
        const int* __restrict__ artist_ids, const int* __restrict__ album_ids,
        const float* __restrict__ user_w,   const float* __restrict__ dinv,
        __half* __restrict__ x, int I_, int U_, int IB) {
    __shared__ __align__(16) __half Wh[64 * WROW];      // proj_W in fp16
    __shared__ __align__(16) __half feat[4 * 16 * WROW]; // per-wave 16x128

    const int tid  = threadIdx.x;
    const int lane = tid & 63;
    const int wv   = tid >> 6;

    if ((int)blockIdx.x >= IB) {
        // ---- user path: 4 rows per wave ----
        int base = ((int)blockIdx.x - IB) * 16 + wv * 4;
        #pragma unroll
        for (int k = 0; k < 4; ++k) {
            int row = base + k;
            if (row < U_) {
                size_t o = (size_t)row * D + lane;
                float v  = user_w[o];
                float ss = wave_reduce_sum(v * v);
                x[o] = __float2half(dinv[row] * v / fmaxf(sqrtf(ss), 1e-12f));
            }
        }
        return;
    }

    // ---- item path ----
    const int n    = lane & 15;       // d within tile / m within tile
    const int quad = lane >> 4;

    for (int idx = tid; idx < 64 * 128; idx += 256) {
        int d = idx >> 7, k = idx & 127;
        Wh[d * WROW + k] = __float2half(proj_W[idx]);
    }
    __syncthreads();

    half8 bfrag[4][4];
    #pragma unroll
    for (int dg = 0; dg < 4; ++dg)
        #pragma unroll
        for (int c = 0; c < 4; ++c)
            bfrag[dg][c] = *reinterpret_cast<const half8*>(
                &Wh[(dg * 16 + n) * WROW + c * 32 + quad * 8]);

    __half* fw = &feat[wv * 16 * WROW];
    const int itemBase = blockIdx.x * 64 + wv * 16;
    #pragma unroll 4
    for (int it = 0; it < 16; ++it) {
        int item = itemBase + it;
        float a = 0.f, m = 0.f;
        if (item < I_) {
            a = audio[(size_t)item * D + lane];
            int aid = artist_ids[item], bid = album_ids[item];
            m = artist_w[(size_t)aid * D + lane] +
                album_w[(size_t)bid * D + lane];
        }
        fw[it * WROW + lane]      = __float2half(a);
        fw[it * WROW + 64 + lane] = __float2half(m);
    }
    __syncthreads();

    half8 afrag[4];
    #pragma unroll
    for (int c = 0; c < 4; ++c)
        afrag[c] = *reinterpret_cast<const half8*>(
            &fw[n * WROW + c * 32 + quad * 8]);

    f32x4 acc[4];
    #pragma unroll
    for (int dg = 0; dg < 4; ++dg) {
        f32x4 t = {0.f, 0.f, 0.f, 0.f};
        #pragma unroll
        for (int c = 0; c < 4; ++c)
            t = __builtin_amdgcn_mfma_f32_16x16x32_f16(afrag[c], bfrag[dg][c],
                                                       t, 0, 0, 0);
        acc[dg] = t;
    }

    float bias[4];
    #pragma unroll
    for (int dg = 0; dg < 4; ++dg) bias[dg] = proj_b[dg * 16 + n];

    float val[4][4], ss[4];
    #pragma unroll
    for (int r = 0; r < 4; ++r) {
        float s = 0.f;
        #pragma unroll
        for (int dg = 0; dg < 4; ++dg) {
            float v = acc[dg][r] + bias[dg];
            val[dg][r] = v;
            s = fmaf(v, v, s);
        }
        s += __shfl_xor(s, 1, 64);
        s += __shfl_xor(s, 2, 64);
        s += __shfl_xor(s, 4, 64);
        s += __shfl_xor(s, 8, 64);
        ss[r] = s;
    }

    #pragma unroll
    for (int r = 0; r < 4; ++r) {
        int item = itemBase + quad * 4 + r;
        if (item >= I_) continue;
        float inv = dinv[U_ + item] / fmaxf(sqrtf(ss[r]), 1e-12f);
        size_t rowo = (size_t)(U_ + item) * D + n;
        #pragma unroll
        for (int dg = 0; dg < 4; ++dg)
            x[rowo + dg * 16] = __float2half(val[dg][r] * inv);
    }
}

// ---- pass 1: LDS-staged bucket-sorted scatter (R8-verified) with
//      shfl-based local scan (1 barrier instead of 16).
//      rec.x = wfix14<<18|src18 (final ent word), rec.y(out) = dst_local.
__global__ void __launch_bounds__(256) k_scatter1(
        const int* __restrict__ u_idx, const int* __restrict__ i_idx,
        const float* __restrict__ ew,
        uint2* __restrict__ records, int* __restrict__ gCursor,
        int E_, int U_, int NB) {
    __shared__ uint2 s_rec[SCAP];       // 64 KB
    __shared__ int hist[NB2];           // per-bucket counts
    __shared__ int cur[NB2];            // local start, then running cursor
    __shared__ int diff[NB2];           // gbase - local start
    __shared__ int wtot[4];
    const int tid = threadIdx.x;
    const int lane = tid & 63;
    const int wv   = tid >> 6;
    const int e0 = blockIdx.x * PASS1_CHUNK;
    int uu[16], vv[16]; unsigned wq[16];
    for (int b = tid; b < NB2; b += 256) hist[b] = 0;
    __syncthreads();
    #pragma unroll
    for (int j = 0; j < 16; ++j) {
        int e = e0 + j * 256 + tid;
        uu[j] = -1;
        if (e < E_) {
            int u = __builtin_nontemporal_load(u_idx + e);
            int v = U_ + __builtin_nontemporal_load(i_idx + e);
            float w = fmaxf(__builtin_nontemporal_load(ew + e), 1e-6f);
            unsigned wfix = (unsigned)fminf(w * 16384.f + 0.5f, 16383.f);
            uu[j] = u; vv[j] = v; wq[j] = wfix << 18;
            atomicAdd(&hist[u >> 7], 1);
            atomicAdd(&hist[v >> 7], 1);
        }
    }
    __syncthreads();
    // reserve global bases per bucket (counts stay intact in hist)
    for (int b = tid; b < NB; b += 256) {
        int c = hist[b];
        diff[b] = c ? atomicAdd(&gCursor[b], c) : 0;
    }
    // local exclusive scan over buckets -> cur (shfl wave scan + handoff)
    const int b0 = tid * BPT;
    int cc[BPT]; int s = 0;
    #pragma unroll
    for (int k = 0; k < BPT; ++k) {
        int b = b0 + k;
        cc[k] = (b < NB2) ? hist[b] : 0;
        s += cc[k];
    }
    int incl = s;
    #pragma unroll
    for (int off = 1; off < 64; off <<= 1) {
        int t = __shfl_up(incl, off, 64);
        if (lane >= off) incl += t;
    }
    if (lane == 63) wtot[wv] = incl;
    __syncthreads();
    int add = 0;
    #pragma unroll
    for (int w = 0; w < 4; ++w) add += (w < wv) ? wtot[w] : 0;
    int run = incl - s + add;           // exclusive prefix over threads
    #pragma unroll
    for (int k = 0; k < BPT; ++k) {
        int b = b0 + k;
        if (b < NB2) cur[b] = run;
        run += cc[k];
    }
    __syncthreads();
    // diff = gbase - local start (must complete before cur is mutated)
    for (int b = tid; b < NB; b += 256) diff[b] -= cur[b];
    __syncthreads();
    // place records bucket-sorted into LDS
    #pragma unroll
    for (int j = 0; j < 16; ++j) {
        if (uu[j] >= 0) {
            int u = uu[j], v = vv[j];
            int bu = u >> 7, bv = v >> 7;
            int pu = atomicAdd(&cur[bu], 1);
            s_rec[pu] = make_uint2(wq[j] | (unsigned)v,
                                   (unsigned)(u & 127) | ((unsigned)bu << 7));
            int pv = atomicAdd(&cur[bv], 1);
            s_rec[pv] = make_uint2(wq[j] | (unsigned)u,
                                   (unsigned)(v & 127) | ((unsigned)bv << 7));
        }
    }
    __syncthreads();
    // coalesced output: consecutive p -> consecutive addresses per run
    int nE = E_ - e0; if (nE > PASS1_CHUNK) nE = PASS1_CHUNK;
    const int Rtot = (nE > 0) ? 2 * nE : 0;
    for (int p = tid; p < Rtot; p += 256) {
        uint2 r = s_rec[p];
        int b = (int)(r.y >> 7);
        int goff = diff[b] + p;            // gbase + (p - lstart)
        if (goff < BCAP)
            records[(size_t)b * BCAP + goff] = make_uint2(r.x, r.y & 127u);
    }
}

// ---- pass 2: per bucket, LDS counting-sort.  gbase computed inline;
//      shfl-based 128-row scan (1 barrier).  Single NT pass over records.
//      ents[pos] = entword verbatim.  dinv = rsqrt(iw/2^14 + 1).
__global__ void __launch_bounds__(256) k_build(
        const uint2* __restrict__ rec,
        const int* __restrict__ gCursor,
        unsigned* __restrict__ ents, int* __restrict__ rowptr,
        float* __restrict__ dinv, int N_, int NB) {
    __shared__ unsigned      s_ent[BCAP];   // 24064 B
    __shared__ unsigned char s_dl[BCAP];    //  6016 B
    __shared__ int   s_cnt[BROWS];
    __shared__ int   s_cur[BROWS];
    __shared__ int   s_iw[BROWS];
    __shared__ int   s_red[256];
    __shared__ int   wt2[2];
    const int b   = blockIdx.x;
    const int tid = threadIdx.x;
    const int lane = tid & 63;
    const int R   = min(gCursor[b], BCAP);
    if (tid < BROWS) { s_cnt[tid] = 0; s_iw[tid] = 0; }
    // inline exclusive prefix: gbase = sum_{i<b} min(gCursor[i], BCAP)
    int psum = 0;
    for (int i = tid; i < b; i += 256) psum += min(gCursor[i], BCAP);
    s_red[tid] = psum;
    __syncthreads();
    for (int off = 128; off > 0; off >>= 1) {
        if (tid < off) s_red[tid] += s_red[tid + off];
        __syncthreads();
    }
    const int gbase = s_red[0];
    // stage + count in one NT pass over global records
    const unsigned long long* rb8 =
        reinterpret_cast<const unsigned long long*>(rec + (size_t)b * BCAP);
    for (int r = tid; r < R; r += 256) {
        unsigned long long rv = __builtin_nontemporal_load(rb8 + r);
        unsigned vx = (unsigned)rv;
        unsigned vy = (unsigned)(rv >> 32);
        s_ent[r] = vx;
        s_dl[r]  = (unsigned char)vy;
        atomicAdd(&s_cnt[vy & 127u], 1);
    }
    __syncthreads();
    // exclusive scan over 128 rows via 2-wave shfl scan
    int own = (tid < BROWS) ? s_cnt[tid] : 0;
    int incl = own;
    #pragma unroll
    for (int off = 1; off < 64; off <<= 1) {
        int t = __shfl_up(incl, off, 64);
        if (lane >= off) incl += t;
    }
    if (tid < BROWS && lane == 63) wt2[tid >> 6] = incl;
    __syncthreads();
    if (tid < BROWS) {
        int excl = incl - own + ((tid >= 64) ? wt2[0] : 0);
        s_cur[tid] = excl;
        int gid = b * BROWS + tid;
        if (gid < N_) rowptr[gid] = gbase + excl;
    }
    if (b == NB - 1 && tid == 0) rowptr[N_] = gbase + R;
    __syncthreads();
    // place from LDS; ent word stored verbatim; iw accumulates wfix
    for (int r = tid; r < R; r += 256) {
        int dl = (int)s_dl[r];
        unsigned ev = s_ent[r];
        int pos = gbase + atomicAdd(&s_cur[dl], 1);
        ents[pos] = ev;
        atomicAdd(&s_iw[dl], (int)(ev >> 18));
    }
    __syncthreads();
    // dinv = rsqrt(iw/16384 + 1)
    if (tid < BROWS) {
        int gid = b * BROWS + tid;
        if (gid < N_)
            dinv[gid] = 1.0f / sqrtf((float)s_iw[tid] * (1.0f / 16384.0f) + 1.0f);
    }
}

// ---- propagation layer in y-domain: s = y[dst] + 2^-14 * sum wfix*y[src];
//      y_next = dinv^2 * s.  8-lane row groups, half8 (16 B) per lane.
//      MLP-deep (round-2 structure, best measured): group g owns the
//      contiguous span [beg+g*L, beg+(g+1)*L), L=ceil(deg/8), predicated
//      batches of 4.  ents loads CACHED (R10 post-mortem: NT hints on ents
//      cost −6 us/dispatch; ent lines have real cross-wave L2 reuse).
// mode 0: write yn = y1; ysum = y0 + y1
// mode 1: write yn = y2; ysum += y2
// mode 2: out = l2norm(ysum + y3)        (yn unused)
__global__ void __launch_bounds__(256) k_gather(
        const uint4* __restrict__ ys, uint4* __restrict__ yn,
        uint4* __restrict__ ysum, float4* __restrict__ outp,
        const float* __restrict__ dinv, const int* __restrict__ rowptr,
        const unsigned* __restrict__ ents, int N_, int mode) {
    const int lane = threadIdx.x & 63;
    const int g  = lane >> 3;            // edge group 0..7
    const int c8 = lane & 7;             // half8 index within row
    const int wid = __builtin_amdgcn_readfirstlane(
                        (int)((blockIdx.x * blockDim.x + threadIdx.x) >> 6));
    if (wid >= N_) return;
    const int beg = rowptr[wid], end = rowptr[wid + 1];
    const size_t ro = (size_t)wid * 8 + c8;

    // hoisted epilogue operands — issue early, consume after the loop
    const float di = dinv[wid];
    uint4 hold, hsum;
    if (mode == 2 || g < 2)                  hold = ys[ro];
    if (mode == 2 || (mode == 1 && g == 1))  hsum = ysum[ro];

    const int deg = end - beg;
    const int L   = (deg + 7) >> 3;          // per-group contiguous span
    int j         = beg + g * L;
    const int je  = min(j + L, end);

    float a[8] = {0.f, 0.f, 0.f, 0.f, 0.f, 0.f, 0.f, 0.f};
    while (j < je) {
        int m = je - j; if (m > 4) m = 4;
        unsigned e[4];
        uint4 h[4];
        e[0] = ents[j];
        if (m > 1) e[1] = ents[j + 1];
        if (m > 2) e[2] = ents[j + 2];
        if (m > 3) e[3] = ents[j + 3];
        h[0] = ys[(size_t)(e[0] & 0x3FFFFu) * 8 + c8];
        if (m > 1) h[1] = ys[(size_t)(e[1] & 0x3FFFFu) * 8 + c8];
        if (m > 2) h[2] = ys[(size_t)(e[2] & 0x3FFFFu) * 8 + c8];
        if (m > 3) h[3] = ys[(size_t)(e[3] & 0x3FFFFu) * 8 + c8];
        #pragma unroll
        for (int t = 0; t < 4; ++t) {
            if (t < m) {
                float wf = (float)(e[t] >> 18);
                const __half2* hp = reinterpret_cast<const __half2*>(&h[t]);
                #pragma unroll
                for (int i = 0; i < 4; ++i) {
                    float2 f2 = __half22float2(hp[i]);
                    a[2 * i]     = fmaf(wf, f2.x, a[2 * i]);
                    a[2 * i + 1] = fmaf(wf, f2.y, a[2 * i + 1]);
                }
            }
        }
        j += 4;
    }

    // reduce the 8 group partials (lanes sharing c8)
    #pragma unroll
    for (int i = 0; i < 8; ++i) {
        a[i] += __shfl_xor(a[i], 8, 64);
        a[i] += __shfl_xor(a[i], 16, 64);
        a[i] += __shfl_xor(a[i], 32, 64);
    }

    float yold[8]; h8_to_f8(hold, yold);
    float d2 = di * di;
    float fin[8];
    #pragma unroll
    for (int i = 0; i < 8; ++i)
        fin[i] = d2 * fmaf(a[i], 1.0f / 16384.0f, yold[i]);

    if (mode == 2) {
        float vs[8]; h8_to_f8(hsum, vs);
        float vv[8], sq = 0.f;
        #pragma unroll
        for (int i = 0; i < 8; ++i) {
            vv[i] = vs[i] + fin[i];
            sq = fmaf(vv[i], vv[i], sq);
        }
        sq += __shfl_xor(sq, 1, 64);
        sq += __shfl_xor(sq, 2, 64);
        sq += __shfl_xor(sq, 4, 64);
        float inv = 1.0f / fmaxf(sqrtf(sq), 1e-12f);
        if (g == 0) {
            size_t ob = (size_t)wid * 16 + c8 * 2;
            f32x4* op = reinterpret_cast<f32x4*>(outp);
            f32x4 v0 = {vv[0] * inv, vv[1] * inv, vv[2] * inv, vv[3] * inv};
            f32x4 v1 = {vv[4] * inv, vv[5] * inv, vv[6] * inv, vv[7] * inv};
            __builtin_nontemporal_store(v0, op + ob);
            __builtin_nontemporal_store(v1, op + ob + 1);
        }
    } else {
        if (g == 0) yn[ro] = f8_to_h8(fin);
        if (g == 1) {
            float t[8];
            if (mode == 0) {
                #pragma unroll
                for (int i = 0; i < 8; ++i) t[i] = yold[i] + fin[i];
            } else {
                float vs[8]; h8_to_f8(hsum, vs);
                #pragma unroll
                for (int i = 0; i < 8; ++i) t[i] = vs[i] + fin[i];
            }
            ysum[ro] = f8_to_h8(t);
        }
    }
}

extern "C" void kernel_launch(void* const* d_in, const int* in_sizes, int n_in,
                              void* d_out, int out_size, void* d_ws, size_t ws_size,
                              hipStream_t stream) {
    const float* user_w     = (const float*)d_in[0];
    const float* audio      = (const float*)d_in[1];
    const float* artist_w   = (const float*)d_in[2];
    const float* album_w    = (const float*)d_in[3];
    const float* proj_W     = (const float*)d_in[4];
    const float* proj_b     = (const float*)d_in[5];
    const float* ew         = (const float*)d_in[6];
    const int*   u_idx      = (const int*)d_in[7];
    const int*   i_idx      = (const int*)d_in[8];
    const int*   artist_ids = (const int*)d_in[9];
    const int*   album_ids  = (const int*)d_in[10];

    const int U_ = in_sizes[0] / D;
    const int I_ = in_sizes[1] / D;
    const int E_ = in_sizes[6];
    const int N_ = U_ + I_;
    const int NB = (N_ + BROWS - 1) / BROWS;    // 1172

    size_t xbytes = (size_t)N_ * D * sizeof(__half);      // 19.2 MB
    size_t recbytes = (size_t)NB * BCAP * sizeof(uint2);  // 56.4 MB
    size_t rreg = 2 * xbytes > recbytes ? 2 * xbytes : recbytes;

    char* p = (char*)d_ws;
    __half* yA = (__half*)p;            p += xbytes;
    char* R = p;                        p += rreg;
    __half* yB   = (__half*)R;                           // aliases records
    __half* ysum = (__half*)(R + xbytes);                // (records dead by then)
    uint2* records = (uint2*)R;
    unsigned* ents = (unsigned*)p;      p += (size_t)2 * E_ * sizeof(unsigned);
    int*   rowptr = (int*)p;            p += (size_t)(N_ + 1) * 4;
    float* dinv   = (float*)p;          p += (size_t)N_ * 4;
    int*   gCursor    = (int*)p;        p += (size_t)NB * 4;

    hipMemsetAsync(gCursor, 0, (size_t)NB * 4, stream);

    // adjacency build first: scatter -> sort+rowptr+dinv
    k_scatter1<<<(E_ + PASS1_CHUNK - 1) / PASS1_CHUNK, 256, 0, stream>>>(
        u_idx, i_idx, ew, records, gCursor, E_, U_, NB);
    k_build<<<NB, 256, 0, stream>>>(records, gCursor,
                                    ents, rowptr, dinv, N_, NB);

    // L0 embeddings -> yA, pre-scaled by dinv (y0 = dinv * x0), fused kernel
    const int IB = (I_ + 63) / 64;
    const int UB = (U_ + 15) / 16;
    k_l0<<<IB + UB, 256, 0, stream>>>(audio, artist_w, album_w, proj_W, proj_b,
                                      artist_ids, album_ids, user_w, dinv,
                                      yA, I_, U_, IB);

    // 3 layers in y-domain; out = l2norm(y0+y1+y2+y3)
    const int ggrid = (N_ + 3) / 4;
    k_gather<<<ggrid, 256, 0, stream>>>((uint4*)yA, (uint4*)yB, (uint4*)ysum,
                                        (float4*)d_out, dinv, rowptr, ents, N_, 0);
    k_gather<<<ggrid, 256, 0, stream>>>((uint4*)yB, (uint4*)yA, (uint4*)ysum,
                                        (float4*)d_out, dinv, rowptr, ents, N_, 1);
    k_gather<<<ggrid, 256, 0, stream>>>((uint4*)yA, (uint4*)yB, (uint4*)ysum,
                                        (float4*)d_out, dinv, rowptr, ents, N_, 2);
}